// Round 7
// baseline (523.110 us; speedup 1.0000x reference)
//
#include <hip/hip_runtime.h>
#include <hip/hip_bf16.h>

#define Bq 4
#define Tq 2048
#define Dq 1024
#define Hq 16
#define HSq 64
#define EPSq 1e-5f

typedef __attribute__((ext_vector_type(8))) short s16x8;
typedef __attribute__((ext_vector_type(4))) float f32x4;

#define GLL16(g, l)                                                        \
    __builtin_amdgcn_global_load_lds(                                      \
        (const __attribute__((address_space(1))) void*)(g),                \
        (__attribute__((address_space(3))) void*)(l), 16, 0, 0)

#define PH_BAR() do { __builtin_amdgcn_sched_barrier(0);                   \
                      __builtin_amdgcn_s_barrier();                        \
                      __builtin_amdgcn_sched_barrier(0); } while (0)

__device__ __forceinline__ ushort f2bf(float f) {
    union { float f; unsigned u; } x; x.f = f;
    unsigned r = x.u + 0x7fffu + ((x.u >> 16) & 1u);
    return (ushort)(r >> 16);
}

// ---------------- LayerNorm: fp32 out + bf16 out ----------------
__global__ __launch_bounds__(256) void ln_bf16(const float* __restrict__ x,
                                               const float* __restrict__ g,
                                               const float* __restrict__ bb,
                                               float* __restrict__ y,
                                               ushort* __restrict__ y16) {
    __shared__ float sdata[8];
    int row = blockIdx.x;
    const float4* xr = (const float4*)(x + (size_t)row * Dq);
    float4 v = xr[threadIdx.x];
    float s  = v.x + v.y + v.z + v.w;
    float ss = v.x*v.x + v.y*v.y + v.z*v.z + v.w*v.w;
    for (int off = 32; off; off >>= 1) {
        s  += __shfl_down(s,  off);
        ss += __shfl_down(ss, off);
    }
    int lane = threadIdx.x & 63, wid = threadIdx.x >> 6;
    if (lane == 0) { sdata[wid] = s; sdata[4 + wid] = ss; }
    __syncthreads();
    if (threadIdx.x == 0) {
        sdata[0] = sdata[0] + sdata[1] + sdata[2] + sdata[3];
        sdata[4] = sdata[4] + sdata[5] + sdata[6] + sdata[7];
    }
    __syncthreads();
    float mu  = sdata[0] * (1.f / Dq);
    float var = sdata[4] * (1.f / Dq) - mu * mu;
    float inv = rsqrtf(var + EPSq);
    float4 gv = ((const float4*)g)[threadIdx.x];
    float4 bv = ((const float4*)bb)[threadIdx.x];
    float4 o;
    o.x = (v.x - mu) * inv * gv.x + bv.x;
    o.y = (v.y - mu) * inv * gv.y + bv.y;
    o.z = (v.z - mu) * inv * gv.z + bv.z;
    o.w = (v.w - mu) * inv * gv.w + bv.w;
    ((float4*)(y + (size_t)row * Dq))[threadIdx.x] = o;
    ushort4 u4;
    u4.x = f2bf(o.x); u4.y = f2bf(o.y); u4.z = f2bf(o.z); u4.w = f2bf(o.w);
    *(ushort4*)(y16 + (size_t)row * Dq + threadIdx.x * 4) = u4;
}

// ---------------- repack Wq/Wk/Wv [H,D,HS] -> bf16 [3D][D] transposed; Wq scaled by 1/32 ----------------
__global__ __launch_bounds__(256) void repack_qkvT(const float* __restrict__ Wqm,
                                                   const float* __restrict__ Wkm,
                                                   const float* __restrict__ Wvm,
                                                   ushort* __restrict__ out) {
    __shared__ float tile[64][65];
    int bid = blockIdx.x;          // p(3) x hh(16) x kt(16)
    int p  = bid >> 8;
    int hh = (bid >> 4) & 15;
    int kt = bid & 15;
    int k0 = kt * 64;
    const float* W = (p == 0) ? Wqm : ((p == 1) ? Wkm : Wvm);
    float scale = (p == 0) ? 0.03125f : 1.0f;
    int j  = threadIdx.x & 63;
    int i0 = threadIdx.x >> 6;
#pragma unroll
    for (int r = 0; r < 16; r++) {
        int i = r * 4 + i0;
        tile[i][j] = W[(size_t)hh * (Dq * HSq) + (size_t)(k0 + i) * HSq + j];
    }
    __syncthreads();
#pragma unroll
    for (int r = 0; r < 16; r++) {
        int i = r * 4 + i0;
        out[(size_t)(p * Dq + hh * HSq + i) * Dq + k0 + j] = f2bf(tile[j][i] * scale);
    }
}

// ---------------- transpose+cvt: in fp32 [K][N] -> out bf16 [N][K] ----------------
__global__ __launch_bounds__(256) void transpose_cvt(const float* __restrict__ in,
                                                     ushort* __restrict__ out,
                                                     int K, int N) {
    __shared__ float tile[64][65];
    int k0 = blockIdx.y * 64, n0 = blockIdx.x * 64;
    int j  = threadIdx.x & 63;
    int i0 = threadIdx.x >> 6;
#pragma unroll
    for (int r = 0; r < 16; r++) {
        int i = r * 4 + i0;
        tile[i][j] = in[(size_t)(k0 + i) * N + n0 + j];
    }
    __syncthreads();
#pragma unroll
    for (int r = 0; r < 16; r++) {
        int i = r * 4 + i0;
        out[(size_t)(n0 + i) * K + k0 + j] = f2bf(tile[j][i]);
    }
}

// ---------------- bf16 MFMA GEMM, counted-vmcnt 2-phase, 4 blocks/CU ----------------
// C = A[M,K] @ BT[N,K]^T (+bias)(+resid)(+relu).
// BM=BN=128, BK=32, 256 thr (2x2 waves, 64x64 out/wave, acc[4][4]).
// LDS = 40 KiB (A 2-buf, B 3-buf) -> 4 blocks/CU. Ledger: prologue stages
// A(0),B(0),B(1), gate vmcnt(2); per iter t: ph0 reads A+B(n0-1), stages
// A(t+1); ph1 reads B(n2-3), stages B(t+2); gate vmcnt(2); vmcnt(0) at
// t=nkt-2. Band-major map: XCD x owns row-tiles [8x,8x+8); srt fastest ->
// co-resident blocks share <=sr A row-panels in L2 (r6-verified: FETCH
// 266->82 MB).
// LDS XOR-swizzle for 64 B rows (r6 had NONE -> 8.4M conflicts: group =
// 4(row&1)+quad put 8 lanes on 4 banks). Logical chunk q of row r stored
// at phys q ^ ((r>>1)&3), via pre-swizzled GLOBAL source (linear dest,
// rule 21) + same XOR on ds_read. Per quad-phase: 16 lanes -> 2 per 16B
// group = 2/bank = free (m136). f invariant across m/nf/+64-row offsets
// (all = 0 mod 8 rows).
// If vtg != null, col-tiles with col0 >= 2048 (V of the QKV GEMM) are
// written TRANSPOSED to vtg as bf16 [B*H*HS][T] with packed ushort4 stores.
__global__ __launch_bounds__(256, 4) void gemm_bf16(const ushort* __restrict__ A,
                                                    const ushort* __restrict__ BT,
                                                    const float* __restrict__ bias,
                                                    const float* __restrict__ resid,
                                                    void* __restrict__ Cp,
                                                    ushort* __restrict__ vtg,
                                                    int M, int N, int K,
                                                    int lda, int ldc,
                                                    int relu, int out_bf16,
                                                    int sr) {
    // A: 2 slots x [128][32] = 2 x 4096 ushorts; B: 3 slots x [128][32]
    __shared__ ushort lds[2 * 4096 + 3 * 4096];    // 20480 ushorts = 40 KiB
    ushort* Alds = lds;
    ushort* Blds = lds + 2 * 4096;

    int tid = threadIdx.x;
    int w = tid >> 6, lane = tid & 63;
    int lm = lane & 15, quad = lane >> 4;
    int wm = w >> 1, wn = w & 1;                   // 2 x 2 wave grid

    // band-major block map (requires mtiles==64, nwg%8==0; else fallback)
    int bid = blockIdx.x;
    int mtiles = M >> 7, ntiles = N >> 7;
    int rt, ct;
    if (mtiles == 64 && (gridDim.x & 7) == 0) {
        int xcd = bid & 7, l = bid >> 3;
        int band = l / (sr * ntiles);
        int rem  = l - band * sr * ntiles;
        ct = rem / sr;
        int srt = rem - ct * sr;
        rt = xcd * 8 + band * sr + srt;
    } else {
        rt = bid % mtiles; ct = bid / mtiles;
    }
    int row0 = rt << 7, col0 = ct << 7;

    // staging (pre-swizzled source): thread covers row w*16+(lane>>2) (+64),
    // phys chunk lane&3; logical source chunk = (lane&3) ^ ((lane>>3)&3)
    // (f(row) = (row>>1)&3; row parity pairs share f). Each row's 4 lanes
    // still cover its full contiguous 64 B -> coalescing unchanged.
    int srow = w * 16 + (lane >> 2);
    int schk = (lane & 3) ^ ((lane >> 3) & 3);
    const ushort* pA = A  + (size_t)(row0 + srow) * lda + schk * 8;
    const ushort* pB = BT + (size_t)(col0 + srow) * K  + schk * 8;

    auto stageA = [&](int slot, int t) {           // 128x32 tile, 2 GLL/thread
        GLL16(pA + (size_t)t * 32, Alds + slot * 4096 + w * 512);
        GLL16(pA + (size_t)t * 32 + (size_t)64 * lda, Alds + slot * 4096 + 2048 + w * 512);
    };
    auto stageB = [&](int slot, int t) {
        GLL16(pB + (size_t)t * 32, Blds + slot * 4096 + w * 512);
        GLL16(pB + (size_t)t * 32 + (size_t)64 * K, Blds + slot * 4096 + 2048 + w * 512);
    };

    // swizzled ds_read chunk offset (ushort units): logical chunk quad of
    // row lm is at phys quad ^ ((lm>>1)&3)
    int qsw = (quad ^ ((lm >> 1) & 3)) * 8;

    f32x4 zero = {0.f, 0.f, 0.f, 0.f};
    f32x4 acc[4][4];
#pragma unroll
    for (int i = 0; i < 4; i++)
#pragma unroll
        for (int jj = 0; jj < 4; jj++) acc[i][jj] = zero;

    int nkt = K >> 5;                              // K-tiles of 32 (>= 32 here)

    // prologue: A(0)->s0, B(0)->s0, B(1)->s1; gate leaves B(1) in flight
    stageA(0, 0);
    stageB(0, 0);
    stageB(1, 1);
    __builtin_amdgcn_sched_barrier(0);
    asm volatile("s_waitcnt vmcnt(2)" ::: "memory");
    __builtin_amdgcn_s_barrier();
    __builtin_amdgcn_sched_barrier(0);

    int sA = 0, sB = 0;
    for (int t = 0; t < nkt; ++t) {
        const bool stA = (t + 1 < nkt);
        const bool stB = (t + 2 < nkt);
        int sB2 = sB + 2; if (sB2 >= 3) sB2 -= 3;
        const ushort* Ab = Alds + sA * 4096 + (wm * 64 + lm) * 32;
        const ushort* Bb = Blds + sB * 4096 + (wn * 64 + lm) * 32;
        s16x8 a[4], b0[2], b1[2];

        // ---- phase 0: all A frags + B n0-1; stage A(t+1) ----
#pragma unroll
        for (int m = 0; m < 4; m++)
            a[m] = *(const s16x8*)(Ab + m * 512 + qsw);
#pragma unroll
        for (int nf = 0; nf < 2; nf++)
            b0[nf] = *(const s16x8*)(Bb + nf * 512 + qsw);
        if (stA) stageA(sA ^ 1, t + 1);
        PH_BAR();
        __builtin_amdgcn_s_setprio(1);
#pragma unroll
        for (int m = 0; m < 4; m++)
#pragma unroll
            for (int nf = 0; nf < 2; nf++)
                acc[m][nf] = __builtin_amdgcn_mfma_f32_16x16x32_bf16(a[m], b0[nf], acc[m][nf], 0, 0, 0);
        __builtin_amdgcn_s_setprio(0);
        PH_BAR();

        // ---- phase 1: B n2-3; stage B(t+2) ----
#pragma unroll
        for (int nf = 0; nf < 2; nf++)
            b1[nf] = *(const s16x8*)(Bb + (nf + 2) * 512 + qsw);
        if (stB) stageB(sB2, t + 2);
        PH_BAR();
        __builtin_amdgcn_s_setprio(1);
#pragma unroll
        for (int m = 0; m < 4; m++)
#pragma unroll
            for (int nf = 0; nf < 2; nf++)
                acc[m][nf + 2] = __builtin_amdgcn_mfma_f32_16x16x32_bf16(a[m], b1[nf], acc[m][nf + 2], 0, 0, 0);
        __builtin_amdgcn_s_setprio(0);
        __builtin_amdgcn_sched_barrier(0);
        if (stB)      { asm volatile("s_waitcnt vmcnt(2)" ::: "memory"); }
        else if (stA) { asm volatile("s_waitcnt vmcnt(0)" ::: "memory"); }
        if (stA) {
            __builtin_amdgcn_s_barrier();
            __builtin_amdgcn_sched_barrier(0);
        }

        sA ^= 1;
        sB += 1; if (sB >= 3) sB -= 3;
    }

    if (vtg && col0 >= 2048) {
        // V part: write transposed [B*H*HS][T], 4 consecutive t per ushort4
#pragma unroll
        for (int m = 0; m < 4; m++) {
            int r0 = row0 + wm * 64 + m * 16 + quad * 4;   // t base (mult of 4)
            int bb = r0 >> 11;
            int t  = r0 & (Tq - 1);
#pragma unroll
            for (int nf = 0; nf < 4; nf++) {
                int hsg = col0 - 2048 + wn * 64 + nf * 16 + lm;   // 0..1023
                ushort4 u;
                u.x = f2bf(acc[m][nf][0]);
                u.y = f2bf(acc[m][nf][1]);
                u.z = f2bf(acc[m][nf][2]);
                u.w = f2bf(acc[m][nf][3]);
                *(ushort4*)(vtg + ((size_t)(bb * Hq + (hsg >> 6)) * HSq + (hsg & 63)) * Tq + t) = u;
            }
        }
        return;
    }

    float bcol[4];
#pragma unroll
    for (int nf = 0; nf < 4; nf++)
        bcol[nf] = bias ? bias[col0 + wn * 64 + nf * 16 + lm] : 0.f;

#pragma unroll
    for (int m = 0; m < 4; m++) {
#pragma unroll
        for (int p = 0; p < 4; p++) {
            int r = row0 + wm * 64 + m * 16 + quad * 4 + p;
#pragma unroll
            for (int nf = 0; nf < 4; nf++) {
                int cc = col0 + wn * 64 + nf * 16 + lm;
                float v = acc[m][nf][p] + bcol[nf];
                if (relu) v = fmaxf(v, 0.f);
                if (resid) v += resid[(size_t)r * ldc + cc];
                if (out_bf16) ((ushort*)Cp)[(size_t)r * ldc + cc] = f2bf(v);
                else          ((float*)Cp)[(size_t)r * ldc + cc] = v;
            }
        }
    }
}

// ---------------- MFMA flash attention, complement-paired q-tiles ----------------
__global__ __launch_bounds__(256) void attn_mfma(const ushort* __restrict__ qkv,
                                                 const ushort* __restrict__ VtG,
                                                 ushort* __restrict__ o16) {
    __shared__ ushort Ks[64 * 72];
    __shared__ ushort Vt[64 * 64];
    __shared__ ushort Ps[4 * 16 * 72];

    int gid = blockIdx.x;
    int b  = gid >> 8;
    int hh = (gid >> 4) & 15;
    int pr = (gid + 7 * b) & 15;
    int qa = pr;
    int qb = 31 - pr;

    int tid = threadIdx.x;
    int w = tid >> 6, lane = tid & 63;
    int lm = lane & 15, quad = lane >> 4;

    const int rs3 = 3 * Dq;
    const ushort* qbase = qkv + (size_t)(b * Tq) * rs3 + hh * HSq;
    int qra = qa * 64 + w * 16 + lm;
    int qrb = qb * 64 + w * 16 + lm;
    s16x8 aqa0 = *(const s16x8*)(qbase + (size_t)qra * rs3 + quad * 8);
    s16x8 aqa1 = *(const s16x8*)(qbase + (size_t)qra * rs3 + 32 + quad * 8);
    s16x8 aqb0 = *(const s16x8*)(qbase + (size_t)qrb * rs3 + quad * 8);
    s16x8 aqb1 = *(const s16x8*)(qbase + (size_t)qrb * rs3 + 32 + quad * 8);

    s16x8 ones;
#pragma unroll
    for (int j = 0; j < 8; j++) ones[j] = (short)0x3F80;

    f32x4 zero = {0.f, 0.f, 0.f, 0.f};
    f32x4 oa[4], ob[4];
#pragma unroll
    for (int nt = 0; nt < 4; nt++) { oa[nt] = zero; ob[nt] = zero; }
    f32x4 la = zero, lb = zero;

    const ushort* kbase = qkv + (size_t)(b * Tq) * rs3 + Dq + hh * HSq;
    const ushort* vtb = VtG + (size_t)((b * Hq + hh) * HSq) * Tq;

    int kr = tid >> 3, kc = (tid & 7) * 8;
    int vh = tid >> 2, vc0 = (tid & 3) * 8;
    int vswz = (((vh >> 3) ^ vh) & 7) << 3;

    s16x8 kp0 = *(const s16x8*)(kbase + (size_t)kr * rs3 + kc);
    s16x8 kp1 = *(const s16x8*)(kbase + (size_t)(kr + 32) * rs3 + kc);
    s16x8 vp0 = *(const s16x8*)(vtb + (size_t)vh * Tq + vc0);
    s16x8 vp1 = *(const s16x8*)(vtb + (size_t)vh * Tq + vc0 + 32);

    auto do_tile = [&](const s16x8& aq0, const s16x8& aq1,
                       f32x4 (&o_acc)[4], f32x4& l_acc, int diag) {
        f32x4 sacc[4];
#pragma unroll
        for (int kt2 = 0; kt2 < 4; kt2++) {
            const ushort* krp = &Ks[(kt2 * 16 + lm) * 72 + quad * 8];
            s16x8 bk0 = *(const s16x8*)krp;
            s16x8 bk1 = *(const s16x8*)(krp + 32);
            f32x4 t = __builtin_amdgcn_mfma_f32_16x16x32_bf16(aq0, bk0, zero, 0, 0, 0);
            sacc[kt2] = __builtin_amdgcn_mfma_f32_16x16x32_bf16(aq1, bk1, t, 0, 0, 0);
        }
        if (diag) {
#pragma unroll
            for (int kt2 = 0; kt2 < 4; kt2++)
#pragma unroll
                for (int r = 0; r < 4; r++)
                    if (kt2 * 16 + lm > w * 16 + quad * 4 + r) sacc[kt2][r] = -1e30f;
        }
#pragma unroll
        for (int kt2 = 0; kt2 < 4; kt2++)
#pragma unroll
            for (int r = 0; r < 4; r++)
                Ps[(w * 16 + quad * 4 + r) * 72 + kt2 * 16 + lm] = f2bf(__expf(sacc[kt2][r]));

        s16x8 ap0 = *(const s16x8*)&Ps[(w * 16 + lm) * 72 + quad * 8];
        s16x8 ap1 = *(const s16x8*)&Ps[(w * 16 + lm) * 72 + 32 + quad * 8];

#pragma unroll
        for (int nt = 0; nt < 4; nt++) {
            int n = nt * 16 + lm;
            int swz = (((n >> 3) ^ n) & 7) << 3;
            s16x8 bv0 = *(const s16x8*)&Vt[n * 64 + ((quad * 8) ^ swz)];
            s16x8 bv1 = *(const s16x8*)&Vt[n * 64 + ((32 + quad * 8) ^ swz)];
            f32x4 t = __builtin_amdgcn_mfma_f32_16x16x32_bf16(ap0, bv0, o_acc[nt], 0, 0, 0);
            o_acc[nt] = __builtin_amdgcn_mfma_f32_16x16x32_bf16(ap1, bv1, t, 0, 0, 0);
        }
        f32x4 t2 = __builtin_amdgcn_mfma_f32_16x16x32_bf16(ap0, ones, l_acc, 0, 0, 0);
        l_acc = __builtin_amdgcn_mfma_f32_16x16x32_bf16(ap1, ones, t2, 0, 0, 0);
    };

    for (int kt = 0; kt <= qb; kt++) {
        __syncthreads();
        *(s16x8*)&Ks[kr * 72 + kc] = kp0;
        *(s16x8*)&Ks[(kr + 32) * 72 + kc] = kp1;
        *(s16x8*)&Vt[vh * 64 + (vc0 ^ vswz)] = vp0;
        *(s16x8*)&Vt[vh * 64 + ((vc0 + 32) ^ vswz)] = vp1;
        __syncthreads();

        if (kt < qb) {
            const ushort* kb = kbase + (size_t)((kt + 1) * 64) * rs3;
            kp0 = *(const s16x8*)(kb + (size_t)kr * rs3 + kc);
            kp1 = *(const s16x8*)(kb + (size_t)(kr + 32) * rs3 + kc);
            const ushort* vb = vtb + (size_t)vh * Tq + (kt + 1) * 64;
            vp0 = *(const s16x8*)(vb + vc0);
            vp1 = *(const s16x8*)(vb + vc0 + 32);
        }

        do_tile(aqb0, aqb1, ob, lb, kt == qb);
        if (kt <= qa)
            do_tile(aqa0, aqa1, oa, la, kt == qa);
    }

#pragma unroll
    for (int r = 0; r < 4; r++) {
        float inva = 1.f / la[r];
        float invb = 1.f / lb[r];
        size_t rowa = (size_t)(b * Tq + qa * 64 + w * 16 + quad * 4 + r);
        size_t rowb = (size_t)(b * Tq + qb * 64 + w * 16 + quad * 4 + r);
#pragma unroll
        for (int nt = 0; nt < 4; nt++) {
            o16[rowa * Dq + hh * HSq + nt * 16 + lm] = f2bf(oa[nt][r] * inva);
            o16[rowb * Dq + hh * HSq + nt * 16 + lm] = f2bf(ob[nt][r] * invb);
        }
    }
}

extern "C" void kernel_launch(void* const* d_in, const int* in_sizes, int n_in,
                              void* d_out, int out_size, void* d_ws, size_t ws_size,
                              hipStream_t stream) {
    const float* x   = (const float*)d_in[0];
    const float* Wq  = (const float*)d_in[1];
    const float* Wk  = (const float*)d_in[2];
    const float* Wv  = (const float*)d_in[3];
    const float* Wp  = (const float*)d_in[4];
    const float* bp  = (const float*)d_in[5];
    const float* W1  = (const float*)d_in[6];
    const float* b1  = (const float*)d_in[7];
    const float* W2  = (const float*)d_in[8];
    const float* b2  = (const float*)d_in[9];
    const float* g1  = (const float*)d_in[10];
    const float* be1 = (const float*)d_in[11];
    const float* g2  = (const float*)d_in[12];
    const float* be2 = (const float*)d_in[13];
    float* out = (float*)d_out;

    const size_t MB = 1u << 20;
    char* ws = (char*)d_ws;
    float*  slotA = (float*)(ws);              // [0,32)   LN1 out -> LN2 out, fp32
    ushort* qkv   = (ushort*)(ws + 32 * MB);   // [32,80)  qkv bf16 (V third unused)
    float*  pbuf  = (float*)(ws + 32 * MB);    // [32,64)  proj out fp32 (qkv dead after attn)
    ushort* u16   = (ushort*)(ws + 32 * MB);   // [32,96)  FF1 out bf16 (pbuf dead after LN2)
    ushort* slotC = (ushort*)(ws + 96 * MB);   // [96,112) h16 -> o16 -> h2_16, bf16
    ushort* WqkvT = (ushort*)(ws + 112 * MB);  // 6 MB
    ushort* WpT   = (ushort*)(ws + 118 * MB);  // 2 MB
    ushort* W1T   = (ushort*)(ws + 120 * MB);  // 8 MB
    ushort* W2T   = (ushort*)(ws + 128 * MB);  // 8 MB
    ushort* VtG   = (ushort*)(ws + 136 * MB);  // 16 MB V^T bf16 [B*H*HS][T]

    const int rows = Bq * Tq;                  // 8192

    hipLaunchKernelGGL(repack_qkvT, dim3(3 * 16 * 16), dim3(256), 0, stream, Wq, Wk, Wv, WqkvT);
    hipLaunchKernelGGL(transpose_cvt, dim3(Dq / 64, Dq / 64), dim3(256), 0, stream, Wp, WpT, Dq, Dq);
    hipLaunchKernelGGL(transpose_cvt, dim3(4 * Dq / 64, Dq / 64), dim3(256), 0, stream, W1, W1T, Dq, 4 * Dq);
    hipLaunchKernelGGL(transpose_cvt, dim3(Dq / 64, 4 * Dq / 64), dim3(256), 0, stream, W2, W2T, 4 * Dq, Dq);

    // 1. LN1
    hipLaunchKernelGGL(ln_bf16, dim3(rows), dim3(256), 0, stream, x, g1, be1, slotA, slotC);
    // 2. QKV GEMM -> Q,K into qkv bf16; V transposed into VtG  (64 x 24 = 1536 blocks)
    hipLaunchKernelGGL(gemm_bf16, dim3((rows / 128) * (3 * Dq / 128)), dim3(256), 0, stream,
                       slotC, WqkvT, (const float*)nullptr, (const float*)nullptr, (void*)qkv, VtG,
                       rows, 3 * Dq, Dq, Dq, 3 * Dq, 0, 1, 8);
    // 3. attention (complement-paired q-tiles) -> slotC bf16
    hipLaunchKernelGGL(attn_mfma, dim3(Bq * Hq * 16), dim3(256), 0, stream, qkv, VtG, slotC);
    // 4. proj + bias + residual(slotA) -> pbuf fp32  (64 x 8 = 512 blocks)
    hipLaunchKernelGGL(gemm_bf16, dim3((rows / 128) * (Dq / 128)), dim3(256), 0, stream,
                       slotC, WpT, bp, slotA, (void*)pbuf, (ushort*)nullptr,
                       rows, Dq, Dq, Dq, Dq, 0, 0, 8);
    // 5. LN2
    hipLaunchKernelGGL(ln_bf16, dim3(rows), dim3(256), 0, stream, pbuf, g2, be2, slotA, slotC);
    // 6. FF1 + bias + relu -> u16 bf16  (64 x 32 = 2048 blocks)
    hipLaunchKernelGGL(gemm_bf16, dim3((rows / 128) * (4 * Dq / 128)), dim3(256), 0, stream,
                       slotC, W1T, b1, (const float*)nullptr, (void*)u16, (ushort*)nullptr,
                       rows, 4 * Dq, Dq, Dq, 4 * Dq, 1, 1, 8);
    // 7. FF2 + bias + residual(slotA) -> out fp32  (64 x 8 = 512 blocks; sr=4 for K=4096)
    hipLaunchKernelGGL(gemm_bf16, dim3((rows / 128) * (Dq / 128)), dim3(256), 0, stream,
                       u16, W2T, b2, slotA, (void*)out, (ushort*)nullptr,
                       rows, Dq, 4 * Dq, 4 * Dq, Dq, 0, 0, 4);
}

// Round 8
// 515.142 us; speedup vs baseline: 1.0155x; 1.0155x over previous
//
#include <hip/hip_runtime.h>
#include <hip/hip_bf16.h>

#define Bq 4
#define Tq 2048
#define Dq 1024
#define Hq 16
#define HSq 64
#define EPSq 1e-5f

typedef __attribute__((ext_vector_type(8))) short s16x8;
typedef __attribute__((ext_vector_type(4))) float f32x4;

#define GLL16(g, l)                                                        \
    __builtin_amdgcn_global_load_lds(                                      \
        (const __attribute__((address_space(1))) void*)(g),                \
        (__attribute__((address_space(3))) void*)(l), 16, 0, 0)

#define PH_BAR() do { __builtin_amdgcn_sched_barrier(0);                   \
                      __builtin_amdgcn_s_barrier();                        \
                      __builtin_amdgcn_sched_barrier(0); } while (0)

__device__ __forceinline__ ushort f2bf(float f) {
    union { float f; unsigned u; } x; x.f = f;
    unsigned r = x.u + 0x7fffu + ((x.u >> 16) & 1u);
    return (ushort)(r >> 16);
}

// ---------------- LayerNorm: fp32 out + bf16 out ----------------
__global__ __launch_bounds__(256) void ln_bf16(const float* __restrict__ x,
                                               const float* __restrict__ g,
                                               const float* __restrict__ bb,
                                               float* __restrict__ y,
                                               ushort* __restrict__ y16) {
    __shared__ float sdata[8];
    int row = blockIdx.x;
    const float4* xr = (const float4*)(x + (size_t)row * Dq);
    float4 v = xr[threadIdx.x];
    float s  = v.x + v.y + v.z + v.w;
    float ss = v.x*v.x + v.y*v.y + v.z*v.z + v.w*v.w;
    for (int off = 32; off; off >>= 1) {
        s  += __shfl_down(s,  off);
        ss += __shfl_down(ss, off);
    }
    int lane = threadIdx.x & 63, wid = threadIdx.x >> 6;
    if (lane == 0) { sdata[wid] = s; sdata[4 + wid] = ss; }
    __syncthreads();
    if (threadIdx.x == 0) {
        sdata[0] = sdata[0] + sdata[1] + sdata[2] + sdata[3];
        sdata[4] = sdata[4] + sdata[5] + sdata[6] + sdata[7];
    }
    __syncthreads();
    float mu  = sdata[0] * (1.f / Dq);
    float var = sdata[4] * (1.f / Dq) - mu * mu;
    float inv = rsqrtf(var + EPSq);
    float4 gv = ((const float4*)g)[threadIdx.x];
    float4 bv = ((const float4*)bb)[threadIdx.x];
    float4 o;
    o.x = (v.x - mu) * inv * gv.x + bv.x;
    o.y = (v.y - mu) * inv * gv.y + bv.y;
    o.z = (v.z - mu) * inv * gv.z + bv.z;
    o.w = (v.w - mu) * inv * gv.w + bv.w;
    ((float4*)(y + (size_t)row * Dq))[threadIdx.x] = o;
    ushort4 u4;
    u4.x = f2bf(o.x); u4.y = f2bf(o.y); u4.z = f2bf(o.z); u4.w = f2bf(o.w);
    *(ushort4*)(y16 + (size_t)row * Dq + threadIdx.x * 4) = u4;
}

// ---------------- repack Wq/Wk/Wv [H,D,HS] -> bf16 [3D][D] transposed; Wq scaled by 1/32 ----------------
__global__ __launch_bounds__(256) void repack_qkvT(const float* __restrict__ Wqm,
                                                   const float* __restrict__ Wkm,
                                                   const float* __restrict__ Wvm,
                                                   ushort* __restrict__ out) {
    __shared__ float tile[64][65];
    int bid = blockIdx.x;          // p(3) x hh(16) x kt(16)
    int p  = bid >> 8;
    int hh = (bid >> 4) & 15;
    int kt = bid & 15;
    int k0 = kt * 64;
    const float* W = (p == 0) ? Wqm : ((p == 1) ? Wkm : Wvm);
    float scale = (p == 0) ? 0.03125f : 1.0f;
    int j  = threadIdx.x & 63;
    int i0 = threadIdx.x >> 6;
#pragma unroll
    for (int r = 0; r < 16; r++) {
        int i = r * 4 + i0;
        tile[i][j] = W[(size_t)hh * (Dq * HSq) + (size_t)(k0 + i) * HSq + j];
    }
    __syncthreads();
#pragma unroll
    for (int r = 0; r < 16; r++) {
        int i = r * 4 + i0;
        out[(size_t)(p * Dq + hh * HSq + i) * Dq + k0 + j] = f2bf(tile[j][i] * scale);
    }
}

// ---------------- transpose+cvt: in fp32 [K][N] -> out bf16 [N][K] ----------------
__global__ __launch_bounds__(256) void transpose_cvt(const float* __restrict__ in,
                                                     ushort* __restrict__ out,
                                                     int K, int N) {
    __shared__ float tile[64][65];
    int k0 = blockIdx.y * 64, n0 = blockIdx.x * 64;
    int j  = threadIdx.x & 63;
    int i0 = threadIdx.x >> 6;
#pragma unroll
    for (int r = 0; r < 16; r++) {
        int i = r * 4 + i0;
        tile[i][j] = in[(size_t)(k0 + i) * N + n0 + j];
    }
    __syncthreads();
#pragma unroll
    for (int r = 0; r < 16; r++) {
        int i = r * 4 + i0;
        out[(size_t)(n0 + i) * K + k0 + j] = f2bf(tile[j][i]);
    }
}

// ---------------- bf16 MFMA GEMM, counted-vmcnt 2-phase, templated BN ----------------
// C = A[M,K] @ BT[N,K]^T (+bias)(+resid)(+relu).
// BNF = B-frags per wave. BNF=4: BM=BN=128, 40 KiB LDS, 4 blocks/CU
// (r7-proven, byte-identical path). BNF=8: BM=128 BN=256, 64 KiB, 2
// blocks/CU, acc[4][8] -> 12 ds_reads per 32 MFMA (vs 8/16) = -25% LDS
// traffic per MFMA (r7 counters: LDS BW ~63% busy = longest pipe).
// 256 thr, 2x2 waves (64 x BNF*16 out/wave), BK=32.
// Ledger (hand-traced): prologue stages A(0), B(0), B(1); gate vmcnt(G)
// leaves B(1) in flight. Per iter t: ph0 reads A + B lo frags, stages
// A(t+1) [+ B(t+2)h0 if BNF=8]; ph1 reads B hi frags, stages B(t+2)
// [h1]; gate vmcnt(G) drains through A(t+1) leaving B(t+2); vmcnt(0)
// at t=nkt-2. G = 2 (BNF=4) / 4 (BNF=8). WAR: slot of tile t+2 = t-1
// (mod 3), last read before previous gate -> >=1 barrier separation.
// XOR-swizzle for 64 B rows (r7-verified, 0 conflicts): logical chunk q
// of row r at phys q ^ ((r>>1)&3); pre-swizzled global source (linear
// LDS dest, rule 21) + same XOR on ds_read. Row bases all = 0 mod 16 ->
// swizzle term depends on lm only.
// Band-major map: XCD x owns row-tiles [8x,8x+8); srt fastest -> co-
// resident blocks share <=sr A row-panels in L2 (r6-verified 266->82 MB).
// If vtg != null, col-tiles with col0 >= 2048 (V of the QKV GEMM) are
// written TRANSPOSED to vtg as bf16 [B*H*HS][T] with packed ushort4 stores.
template<int BNF>
__global__ __launch_bounds__(256, (BNF == 8) ? 2 : 4)
void gemm_bf16(const ushort* __restrict__ A,
               const ushort* __restrict__ BT,
               const float* __restrict__ bias,
               const float* __restrict__ resid,
               void* __restrict__ Cp,
               ushort* __restrict__ vtg,
               int M, int N, int K,
               int lda, int ldc,
               int relu, int out_bf16,
               int sr) {
    constexpr int BN = BNF * 32;                   // 128 or 256
    constexpr int BSLOT = BN * 32;                 // ushorts per B slot
    __shared__ ushort lds[2 * 4096 + 3 * BSLOT];   // 40 or 64 KiB
    ushort* Alds = lds;
    ushort* Blds = lds + 2 * 4096;

    int tid = threadIdx.x;
    int w = tid >> 6, lane = tid & 63;
    int lm = lane & 15, quad = lane >> 4;
    int wm = w >> 1, wn = w & 1;                   // 2 x 2 wave grid

    // band-major block map (requires mtiles==64, nwg%8==0; else fallback)
    int bid = blockIdx.x;
    int mtiles = M >> 7, ntiles = N / BN;
    int rt, ct;
    if (mtiles == 64 && (gridDim.x & 7) == 0) {
        int xcd = bid & 7, l = bid >> 3;
        int band = l / (sr * ntiles);
        int rem  = l - band * sr * ntiles;
        ct = rem / sr;
        int srt = rem - ct * sr;
        rt = xcd * 8 + band * sr + srt;
    } else {
        rt = bid % mtiles; ct = bid / mtiles;
    }
    int row0 = rt << 7, col0 = ct * BN;

    // staging (pre-swizzled source): thread covers row w*16+(lane>>2) (+64),
    // phys chunk lane&3; logical source chunk = (lane&3) ^ ((lane>>3)&3).
    int srow = w * 16 + (lane >> 2);
    int schk = (lane & 3) ^ ((lane >> 3) & 3);
    const ushort* pA = A  + (size_t)(row0 + srow) * lda + schk * 8;
    const ushort* pB = BT + (size_t)(col0 + srow) * K  + schk * 8;

    auto stageA = [&](int slot, int t) {           // [128][32] tile, 2 GLL
        GLL16(pA + (size_t)t * 32, Alds + slot * 4096 + w * 512);
        GLL16(pA + (size_t)t * 32 + (size_t)64 * lda, Alds + slot * 4096 + 2048 + w * 512);
    };
    auto stageBh = [&](int slot, int t, int h) {   // [128][32] half, 2 GLL
        const ushort* g = pB + (size_t)t * 32 + (size_t)(h * 128) * K;
        ushort* l = Blds + slot * BSLOT + h * 4096 + w * 512;
        GLL16(g, l);
        GLL16(g + (size_t)64 * K, l + 2048);
    };

    // swizzled ds_read chunk offset (ushort units)
    int qsw = (quad ^ ((lm >> 1) & 3)) * 8;

    f32x4 zero = {0.f, 0.f, 0.f, 0.f};
    f32x4 acc[4][BNF];
#pragma unroll
    for (int i = 0; i < 4; i++)
#pragma unroll
        for (int jj = 0; jj < BNF; jj++) acc[i][jj] = zero;

    int nkt = K >> 5;                              // K-tiles of 32 (>= 32 here)

    // prologue: A(0)->s0, B(0)->s0, B(1)->s1; gate leaves B(1) in flight
    stageA(0, 0);
    stageBh(0, 0, 0);
    if constexpr (BNF == 8) stageBh(0, 0, 1);
    stageBh(1, 1, 0);
    if constexpr (BNF == 8) stageBh(1, 1, 1);
    __builtin_amdgcn_sched_barrier(0);
    if constexpr (BNF == 8) { asm volatile("s_waitcnt vmcnt(4)" ::: "memory"); }
    else                    { asm volatile("s_waitcnt vmcnt(2)" ::: "memory"); }
    __builtin_amdgcn_s_barrier();
    __builtin_amdgcn_sched_barrier(0);

    int sA = 0, sB = 0;
    for (int t = 0; t < nkt; ++t) {
        const bool stA = (t + 1 < nkt);
        const bool stB = (t + 2 < nkt);
        int sB2 = sB + 2; if (sB2 >= 3) sB2 -= 3;
        const ushort* Ab = Alds + sA * 4096  + (wm * 64 + lm) * 32;
        const ushort* Bb = Blds + sB * BSLOT + (wn * (BNF * 16) + lm) * 32;
        s16x8 a[4], b0[BNF / 2], b1[BNF / 2];

        // ---- phase 0: all A frags + B lo frags; stage A(t+1) [+B(t+2)h0] ----
#pragma unroll
        for (int m = 0; m < 4; m++)
            a[m] = *(const s16x8*)(Ab + m * 512 + qsw);
#pragma unroll
        for (int nf = 0; nf < BNF / 2; nf++)
            b0[nf] = *(const s16x8*)(Bb + nf * 512 + qsw);
        if (stA) stageA(sA ^ 1, t + 1);
        if constexpr (BNF == 8) { if (stB) stageBh(sB2, t + 2, 0); }
        PH_BAR();
        __builtin_amdgcn_s_setprio(1);
#pragma unroll
        for (int m = 0; m < 4; m++)
#pragma unroll
            for (int nf = 0; nf < BNF / 2; nf++)
                acc[m][nf] = __builtin_amdgcn_mfma_f32_16x16x32_bf16(a[m], b0[nf], acc[m][nf], 0, 0, 0);
        __builtin_amdgcn_s_setprio(0);
        PH_BAR();

        // ---- phase 1: B hi frags; stage B(t+2) [h1] ----
#pragma unroll
        for (int nf = 0; nf < BNF / 2; nf++)
            b1[nf] = *(const s16x8*)(Bb + (nf + BNF / 2) * 512 + qsw);
        if constexpr (BNF == 8) { if (stB) stageBh(sB2, t + 2, 1); }
        else                    { if (stB) stageBh(sB2, t + 2, 0); }
        PH_BAR();
        __builtin_amdgcn_s_setprio(1);
#pragma unroll
        for (int m = 0; m < 4; m++)
#pragma unroll
            for (int nf = 0; nf < BNF / 2; nf++)
                acc[m][nf + BNF / 2] = __builtin_amdgcn_mfma_f32_16x16x32_bf16(a[m], b1[nf], acc[m][nf + BNF / 2], 0, 0, 0);
        __builtin_amdgcn_s_setprio(0);
        __builtin_amdgcn_sched_barrier(0);
        if (stB) {
            if constexpr (BNF == 8) { asm volatile("s_waitcnt vmcnt(4)" ::: "memory"); }
            else                    { asm volatile("s_waitcnt vmcnt(2)" ::: "memory"); }
        } else if (stA) {
            asm volatile("s_waitcnt vmcnt(0)" ::: "memory");
        }
        if (stA) {
            __builtin_amdgcn_s_barrier();
            __builtin_amdgcn_sched_barrier(0);
        }

        sA ^= 1;
        sB += 1; if (sB >= 3) sB -= 3;
    }

    if (vtg && col0 >= 2048) {
        // V part: write transposed [B*H*HS][T], 4 consecutive t per ushort4
#pragma unroll
        for (int m = 0; m < 4; m++) {
            int r0 = row0 + wm * 64 + m * 16 + quad * 4;   // t base (mult of 4)
            int bb = r0 >> 11;
            int t  = r0 & (Tq - 1);
#pragma unroll
            for (int nf = 0; nf < BNF; nf++) {
                int hsg = col0 - 2048 + wn * (BNF * 16) + nf * 16 + lm;   // 0..1023
                ushort4 u;
                u.x = f2bf(acc[m][nf][0]);
                u.y = f2bf(acc[m][nf][1]);
                u.z = f2bf(acc[m][nf][2]);
                u.w = f2bf(acc[m][nf][3]);
                *(ushort4*)(vtg + ((size_t)(bb * Hq + (hsg >> 6)) * HSq + (hsg & 63)) * Tq + t) = u;
            }
        }
        return;
    }

    float bcol[BNF];
#pragma unroll
    for (int nf = 0; nf < BNF; nf++)
        bcol[nf] = bias ? bias[col0 + wn * (BNF * 16) + nf * 16 + lm] : 0.f;

#pragma unroll
    for (int m = 0; m < 4; m++) {
#pragma unroll
        for (int p = 0; p < 4; p++) {
            int r = row0 + wm * 64 + m * 16 + quad * 4 + p;
#pragma unroll
            for (int nf = 0; nf < BNF; nf++) {
                int cc = col0 + wn * (BNF * 16) + nf * 16 + lm;
                float v = acc[m][nf][p] + bcol[nf];
                if (relu) v = fmaxf(v, 0.f);
                if (resid) v += resid[(size_t)r * ldc + cc];
                if (out_bf16) ((ushort*)Cp)[(size_t)r * ldc + cc] = f2bf(v);
                else          ((float*)Cp)[(size_t)r * ldc + cc] = v;
            }
        }
    }
}

// ---------------- MFMA flash attention, complement-paired q-tiles ----------------
__global__ __launch_bounds__(256) void attn_mfma(const ushort* __restrict__ qkv,
                                                 const ushort* __restrict__ VtG,
                                                 ushort* __restrict__ o16) {
    __shared__ ushort Ks[64 * 72];
    __shared__ ushort Vt[64 * 64];
    __shared__ ushort Ps[4 * 16 * 72];

    int gid = blockIdx.x;
    int b  = gid >> 8;
    int hh = (gid >> 4) & 15;
    int pr = (gid + 7 * b) & 15;
    int qa = pr;
    int qb = 31 - pr;

    int tid = threadIdx.x;
    int w = tid >> 6, lane = tid & 63;
    int lm = lane & 15, quad = lane >> 4;

    const int rs3 = 3 * Dq;
    const ushort* qbase = qkv + (size_t)(b * Tq) * rs3 + hh * HSq;
    int qra = qa * 64 + w * 16 + lm;
    int qrb = qb * 64 + w * 16 + lm;
    s16x8 aqa0 = *(const s16x8*)(qbase + (size_t)qra * rs3 + quad * 8);
    s16x8 aqa1 = *(const s16x8*)(qbase + (size_t)qra * rs3 + 32 + quad * 8);
    s16x8 aqb0 = *(const s16x8*)(qbase + (size_t)qrb * rs3 + quad * 8);
    s16x8 aqb1 = *(const s16x8*)(qbase + (size_t)qrb * rs3 + 32 + quad * 8);

    s16x8 ones;
#pragma unroll
    for (int j = 0; j < 8; j++) ones[j] = (short)0x3F80;

    f32x4 zero = {0.f, 0.f, 0.f, 0.f};
    f32x4 oa[4], ob[4];
#pragma unroll
    for (int nt = 0; nt < 4; nt++) { oa[nt] = zero; ob[nt] = zero; }
    f32x4 la = zero, lb = zero;

    const ushort* kbase = qkv + (size_t)(b * Tq) * rs3 + Dq + hh * HSq;
    const ushort* vtb = VtG + (size_t)((b * Hq + hh) * HSq) * Tq;

    int kr = tid >> 3, kc = (tid & 7) * 8;
    int vh = tid >> 2, vc0 = (tid & 3) * 8;
    int vswz = (((vh >> 3) ^ vh) & 7) << 3;

    s16x8 kp0 = *(const s16x8*)(kbase + (size_t)kr * rs3 + kc);
    s16x8 kp1 = *(const s16x8*)(kbase + (size_t)(kr + 32) * rs3 + kc);
    s16x8 vp0 = *(const s16x8*)(vtb + (size_t)vh * Tq + vc0);
    s16x8 vp1 = *(const s16x8*)(vtb + (size_t)vh * Tq + vc0 + 32);

    auto do_tile = [&](const s16x8& aq0, const s16x8& aq1,
                       f32x4 (&o_acc)[4], f32x4& l_acc, int diag) {
        f32x4 sacc[4];
#pragma unroll
        for (int kt2 = 0; kt2 < 4; kt2++) {
            const ushort* krp = &Ks[(kt2 * 16 + lm) * 72 + quad * 8];
            s16x8 bk0 = *(const s16x8*)krp;
            s16x8 bk1 = *(const s16x8*)(krp + 32);
            f32x4 t = __builtin_amdgcn_mfma_f32_16x16x32_bf16(aq0, bk0, zero, 0, 0, 0);
            sacc[kt2] = __builtin_amdgcn_mfma_f32_16x16x32_bf16(aq1, bk1, t, 0, 0, 0);
        }
        if (diag) {
#pragma unroll
            for (int kt2 = 0; kt2 < 4; kt2++)
#pragma unroll
                for (int r = 0; r < 4; r++)
                    if (kt2 * 16 + lm > w * 16 + quad * 4 + r) sacc[kt2][r] = -1e30f;
        }
#pragma unroll
        for (int kt2 = 0; kt2 < 4; kt2++)
#pragma unroll
            for (int r = 0; r < 4; r++)
                Ps[(w * 16 + quad * 4 + r) * 72 + kt2 * 16 + lm] = f2bf(__expf(sacc[kt2][r]));

        s16x8 ap0 = *(const s16x8*)&Ps[(w * 16 + lm) * 72 + quad * 8];
        s16x8 ap1 = *(const s16x8*)&Ps[(w * 16 + lm) * 72 + 32 + quad * 8];

#pragma unroll
        for (int nt = 0; nt < 4; nt++) {
            int n = nt * 16 + lm;
            int swz = (((n >> 3) ^ n) & 7) << 3;
            s16x8 bv0 = *(const s16x8*)&Vt[n * 64 + ((quad * 8) ^ swz)];
            s16x8 bv1 = *(const s16x8*)&Vt[n * 64 + ((32 + quad * 8) ^ swz)];
            f32x4 t = __builtin_amdgcn_mfma_f32_16x16x32_bf16(ap0, bv0, o_acc[nt], 0, 0, 0);
            o_acc[nt] = __builtin_amdgcn_mfma_f32_16x16x32_bf16(ap1, bv1, t, 0, 0, 0);
        }
        f32x4 t2 = __builtin_amdgcn_mfma_f32_16x16x32_bf16(ap0, ones, l_acc, 0, 0, 0);
        l_acc = __builtin_amdgcn_mfma_f32_16x16x32_bf16(ap1, ones, t2, 0, 0, 0);
    };

    for (int kt = 0; kt <= qb; kt++) {
        __syncthreads();
        *(s16x8*)&Ks[kr * 72 + kc] = kp0;
        *(s16x8*)&Ks[(kr + 32) * 72 + kc] = kp1;
        *(s16x8*)&Vt[vh * 64 + (vc0 ^ vswz)] = vp0;
        *(s16x8*)&Vt[vh * 64 + ((vc0 + 32) ^ vswz)] = vp1;
        __syncthreads();

        if (kt < qb) {
            const ushort* kb = kbase + (size_t)((kt + 1) * 64) * rs3;
            kp0 = *(const s16x8*)(kb + (size_t)kr * rs3 + kc);
            kp1 = *(const s16x8*)(kb + (size_t)(kr + 32) * rs3 + kc);
            const ushort* vb = vtb + (size_t)vh * Tq + (kt + 1) * 64;
            vp0 = *(const s16x8*)(vb + vc0);
            vp1 = *(const s16x8*)(vb + vc0 + 32);
        }

        do_tile(aqb0, aqb1, ob, lb, kt == qb);
        if (kt <= qa)
            do_tile(aqa0, aqa1, oa, la, kt == qa);
    }

#pragma unroll
    for (int r = 0; r < 4; r++) {
        float inva = 1.f / la[r];
        float invb = 1.f / lb[r];
        size_t rowa = (size_t)(b * Tq + qa * 64 + w * 16 + quad * 4 + r);
        size_t rowb = (size_t)(b * Tq + qb * 64 + w * 16 + quad * 4 + r);
#pragma unroll
        for (int nt = 0; nt < 4; nt++) {
            o16[rowa * Dq + hh * HSq + nt * 16 + lm] = f2bf(oa[nt][r] * inva);
            o16[rowb * Dq + hh * HSq + nt * 16 + lm] = f2bf(ob[nt][r] * invb);
        }
    }
}

extern "C" void kernel_launch(void* const* d_in, const int* in_sizes, int n_in,
                              void* d_out, int out_size, void* d_ws, size_t ws_size,
                              hipStream_t stream) {
    const float* x   = (const float*)d_in[0];
    const float* Wq  = (const float*)d_in[1];
    const float* Wk  = (const float*)d_in[2];
    const float* Wv  = (const float*)d_in[3];
    const float* Wp  = (const float*)d_in[4];
    const float* bp  = (const float*)d_in[5];
    const float* W1  = (const float*)d_in[6];
    const float* b1  = (const float*)d_in[7];
    const float* W2  = (const float*)d_in[8];
    const float* b2  = (const float*)d_in[9];
    const float* g1  = (const float*)d_in[10];
    const float* be1 = (const float*)d_in[11];
    const float* g2  = (const float*)d_in[12];
    const float* be2 = (const float*)d_in[13];
    float* out = (float*)d_out;

    const size_t MB = 1u << 20;
    char* ws = (char*)d_ws;
    float*  slotA = (float*)(ws);              // [0,32)   LN1 out -> LN2 out, fp32
    ushort* qkv   = (ushort*)(ws + 32 * MB);   // [32,80)  qkv bf16 (V third unused)
    float*  pbuf  = (float*)(ws + 32 * MB);    // [32,64)  proj out fp32 (qkv dead after attn)
    ushort* u16   = (ushort*)(ws + 32 * MB);   // [32,96)  FF1 out bf16 (pbuf dead after LN2)
    ushort* slotC = (ushort*)(ws + 96 * MB);   // [96,112) h16 -> o16 -> h2_16, bf16
    ushort* WqkvT = (ushort*)(ws + 112 * MB);  // 6 MB
    ushort* WpT   = (ushort*)(ws + 118 * MB);  // 2 MB
    ushort* W1T   = (ushort*)(ws + 120 * MB);  // 8 MB
    ushort* W2T   = (ushort*)(ws + 128 * MB);  // 8 MB
    ushort* VtG   = (ushort*)(ws + 136 * MB);  // 16 MB V^T bf16 [B*H*HS][T]

    const int rows = Bq * Tq;                  // 8192

    hipLaunchKernelGGL(repack_qkvT, dim3(3 * 16 * 16), dim3(256), 0, stream, Wq, Wk, Wv, WqkvT);
    hipLaunchKernelGGL(transpose_cvt, dim3(Dq / 64, Dq / 64), dim3(256), 0, stream, Wp, WpT, Dq, Dq);
    hipLaunchKernelGGL(transpose_cvt, dim3(4 * Dq / 64, Dq / 64), dim3(256), 0, stream, W1, W1T, Dq, 4 * Dq);
    hipLaunchKernelGGL(transpose_cvt, dim3(Dq / 64, 4 * Dq / 64), dim3(256), 0, stream, W2, W2T, 4 * Dq, Dq);

    // 1. LN1
    hipLaunchKernelGGL(ln_bf16, dim3(rows), dim3(256), 0, stream, x, g1, be1, slotA, slotC);
    // 2. QKV GEMM (BN=256) -> Q,K into qkv bf16; V transposed into VtG  (64 x 12 = 768 blocks)
    hipLaunchKernelGGL(gemm_bf16<8>, dim3((rows / 128) * (3 * Dq / 256)), dim3(256), 0, stream,
                       slotC, WqkvT, (const float*)nullptr, (const float*)nullptr, (void*)qkv, VtG,
                       rows, 3 * Dq, Dq, Dq, 3 * Dq, 0, 1, 8);
    // 3. attention (complement-paired q-tiles) -> slotC bf16
    hipLaunchKernelGGL(attn_mfma, dim3(Bq * Hq * 16), dim3(256), 0, stream, qkv, VtG, slotC);
    // 4. proj + bias + residual(slotA) -> pbuf fp32  (BN=128, 64 x 8 = 512 blocks)
    hipLaunchKernelGGL(gemm_bf16<4>, dim3((rows / 128) * (Dq / 128)), dim3(256), 0, stream,
                       slotC, WpT, bp, slotA, (void*)pbuf, (ushort*)nullptr,
                       rows, Dq, Dq, Dq, Dq, 0, 0, 8);
    // 5. LN2
    hipLaunchKernelGGL(ln_bf16, dim3(rows), dim3(256), 0, stream, pbuf, g2, be2, slotA, slotC);
    // 6. FF1 + bias + relu (BN=256) -> u16 bf16  (64 x 16 = 1024 blocks)
    hipLaunchKernelGGL(gemm_bf16<8>, dim3((rows / 128) * (4 * Dq / 256)), dim3(256), 0, stream,
                       slotC, W1T, b1, (const float*)nullptr, (void*)u16, (ushort*)nullptr,
                       rows, 4 * Dq, Dq, Dq, 4 * Dq, 1, 1, 8);
    // 7. FF2 + bias + residual(slotA) (BN=128) -> out fp32  (64 x 8 = 512 blocks; sr=4 for K=4096)
    hipLaunchKernelGGL(gemm_bf16<4>, dim3((rows / 128) * (Dq / 128)), dim3(256), 0, stream,
                       u16, W2T, b2, slotA, (void*)out, (ushort*)nullptr,
                       rows, Dq, 4 * Dq, 4 * Dq, Dq, 0, 0, 4);
}

// Round 10
// 503.666 us; speedup vs baseline: 1.0386x; 1.0228x over previous
//
#include <hip/hip_runtime.h>
#include <hip/hip_bf16.h>

#define Bq 4
#define Tq 2048
#define Dq 1024
#define Hq 16
#define HSq 64
#define EPSq 1e-5f

typedef __attribute__((ext_vector_type(8))) short s16x8;
typedef __attribute__((ext_vector_type(4))) float f32x4;

#define GLL16(g, l)                                                        \
    __builtin_amdgcn_global_load_lds(                                      \
        (const __attribute__((address_space(1))) void*)(g),                \
        (__attribute__((address_space(3))) void*)(l), 16, 0, 0)

__device__ __forceinline__ ushort f2bf(float f) {
    union { float f; unsigned u; } x; x.f = f;
    unsigned r = x.u + 0x7fffu + ((x.u >> 16) & 1u);
    return (ushort)(r >> 16);
}

// ---------------- LayerNorm: fp32 out + bf16 out ----------------
__global__ __launch_bounds__(256) void ln_bf16(const float* __restrict__ x,
                                               const float* __restrict__ g,
                                               const float* __restrict__ bb,
                                               float* __restrict__ y,
                                               ushort* __restrict__ y16) {
    __shared__ float sdata[8];
    int row = blockIdx.x;
    const float4* xr = (const float4*)(x + (size_t)row * Dq);
    float4 v = xr[threadIdx.x];
    float s  = v.x + v.y + v.z + v.w;
    float ss = v.x*v.x + v.y*v.y + v.z*v.z + v.w*v.w;
    for (int off = 32; off; off >>= 1) {
        s  += __shfl_down(s,  off);
        ss += __shfl_down(ss, off);
    }
    int lane = threadIdx.x & 63, wid = threadIdx.x >> 6;
    if (lane == 0) { sdata[wid] = s; sdata[4 + wid] = ss; }
    __syncthreads();
    if (threadIdx.x == 0) {
        sdata[0] = sdata[0] + sdata[1] + sdata[2] + sdata[3];
        sdata[4] = sdata[4] + sdata[5] + sdata[6] + sdata[7];
    }
    __syncthreads();
    float mu  = sdata[0] * (1.f / Dq);
    float var = sdata[4] * (1.f / Dq) - mu * mu;
    float inv = rsqrtf(var + EPSq);
    float4 gv = ((const float4*)g)[threadIdx.x];
    float4 bv = ((const float4*)bb)[threadIdx.x];
    float4 o;
    o.x = (v.x - mu) * inv * gv.x + bv.x;
    o.y = (v.y - mu) * inv * gv.y + bv.y;
    o.z = (v.z - mu) * inv * gv.z + bv.z;
    o.w = (v.w - mu) * inv * gv.w + bv.w;
    ((float4*)(y + (size_t)row * Dq))[threadIdx.x] = o;
    ushort4 u4;
    u4.x = f2bf(o.x); u4.y = f2bf(o.y); u4.z = f2bf(o.z); u4.w = f2bf(o.w);
    *(ushort4*)(y16 + (size_t)row * Dq + threadIdx.x * 4) = u4;
}

// ---------------- repack Wq/Wk/Wv [H,D,HS] -> bf16 [3D][D] transposed; Wq scaled by 1/32 ----------------
__global__ __launch_bounds__(256) void repack_qkvT(const float* __restrict__ Wqm,
                                                   const float* __restrict__ Wkm,
                                                   const float* __restrict__ Wvm,
                                                   ushort* __restrict__ out) {
    __shared__ float tile[64][65];
    int bid = blockIdx.x;          // p(3) x hh(16) x kt(16)
    int p  = bid >> 8;
    int hh = (bid >> 4) & 15;
    int kt = bid & 15;
    int k0 = kt * 64;
    const float* W = (p == 0) ? Wqm : ((p == 1) ? Wkm : Wvm);
    float scale = (p == 0) ? 0.03125f : 1.0f;
    int j  = threadIdx.x & 63;
    int i0 = threadIdx.x >> 6;
#pragma unroll
    for (int r = 0; r < 16; r++) {
        int i = r * 4 + i0;
        tile[i][j] = W[(size_t)hh * (Dq * HSq) + (size_t)(k0 + i) * HSq + j];
    }
    __syncthreads();
#pragma unroll
    for (int r = 0; r < 16; r++) {
        int i = r * 4 + i0;
        out[(size_t)(p * Dq + hh * HSq + i) * Dq + k0 + j] = f2bf(tile[j][i] * scale);
    }
}

// ---------------- transpose+cvt: in fp32 [K][N] -> out bf16 [N][K] ----------------
__global__ __launch_bounds__(256) void transpose_cvt(const float* __restrict__ in,
                                                     ushort* __restrict__ out,
                                                     int K, int N) {
    __shared__ float tile[64][65];
    int k0 = blockIdx.y * 64, n0 = blockIdx.x * 64;
    int j  = threadIdx.x & 63;
    int i0 = threadIdx.x >> 6;
#pragma unroll
    for (int r = 0; r < 16; r++) {
        int i = r * 4 + i0;
        tile[i][j] = in[(size_t)(k0 + i) * N + n0 + j];
    }
    __syncthreads();
#pragma unroll
    for (int r = 0; r < 16; r++) {
        int i = r * 4 + i0;
        out[(size_t)(n0 + i) * K + k0 + j] = f2bf(tile[j][i]);
    }
}

// ---------------- bf16 MFMA GEMM, 1-barrier counted-vmcnt loop, templated BN ----------------
// RETEST of round-9 kernel (failed with no counters; same signature as the
// round-1 infra flake). Ledger re-audited: RAW covered by prev iter's
// gate+barrier; WAR targets last read >=1 barrier earlier; barriers
// block-uniform; drain cases traced. Identical source resubmitted for a
// clean infra A/B. If it fails again -> revert to r8 4-barrier loop.
//
// C = A[M,K] @ BT[N,K]^T (+bias)(+resid)(+relu).
// BNF=4: BM=BN=128, 40 KiB LDS, 4 blocks/CU. BNF=8: BM=128 BN=256,
// 64 KiB, 2 blocks/CU. 256 thr, 2x2 waves, BK=32.
// T3 "minimum 2-phase" schedule: ONE barrier + ONE counted gate per
// K-tile. Per iter t: issue stage A(t+1)+B(t+2) | sched_barrier |
// ds_read tile t frags | MFMA | gate vmcnt(G) | s_barrier. G=2 (BNF=4)
// / 4 (BNF=8) leaves exactly B(t+2) in flight; vmcnt(0) at t=nkt-2.
// XOR-swizzle for 64 B rows (r7-verified, 0 conflicts). Band-major map
// (r6-verified FETCH 266->82 MB).
// If vtg != null, col-tiles with col0 >= 2048 (V of the QKV GEMM) are
// written TRANSPOSED to vtg as bf16 [B*H*HS][T] with packed ushort4 stores.
template<int BNF>
__global__ __launch_bounds__(256, (BNF == 8) ? 2 : 4)
void gemm_bf16(const ushort* __restrict__ A,
               const ushort* __restrict__ BT,
               const float* __restrict__ bias,
               const float* __restrict__ resid,
               void* __restrict__ Cp,
               ushort* __restrict__ vtg,
               int M, int N, int K,
               int lda, int ldc,
               int relu, int out_bf16,
               int sr) {
    constexpr int BN = BNF * 32;                   // 128 or 256
    constexpr int BSLOT = BN * 32;                 // ushorts per B slot
    __shared__ ushort lds[2 * 4096 + 3 * BSLOT];   // 40 or 64 KiB
    ushort* Alds = lds;
    ushort* Blds = lds + 2 * 4096;

    int tid = threadIdx.x;
    int w = tid >> 6, lane = tid & 63;
    int lm = lane & 15, quad = lane >> 4;
    int wm = w >> 1, wn = w & 1;                   // 2 x 2 wave grid

    // band-major block map (requires mtiles==64, nwg%8==0; else fallback)
    int bid = blockIdx.x;
    int mtiles = M >> 7, ntiles = N / BN;
    int rt, ct;
    if (mtiles == 64 && (gridDim.x & 7) == 0) {
        int xcd = bid & 7, l = bid >> 3;
        int band = l / (sr * ntiles);
        int rem  = l - band * sr * ntiles;
        ct = rem / sr;
        int srt = rem - ct * sr;
        rt = xcd * 8 + band * sr + srt;
    } else {
        rt = bid % mtiles; ct = bid / mtiles;
    }
    int row0 = rt << 7, col0 = ct * BN;

    // staging (pre-swizzled source): thread covers row w*16+(lane>>2) (+64),
    // phys chunk lane&3; logical source chunk = (lane&3) ^ ((lane>>3)&3).
    int srow = w * 16 + (lane >> 2);
    int schk = (lane & 3) ^ ((lane >> 3) & 3);
    const ushort* pA = A  + (size_t)(row0 + srow) * lda + schk * 8;
    const ushort* pB = BT + (size_t)(col0 + srow) * K  + schk * 8;

    auto stageA = [&](int slot, int t) {           // [128][32] tile, 2 GLL
        GLL16(pA + (size_t)t * 32, Alds + slot * 4096 + w * 512);
        GLL16(pA + (size_t)t * 32 + (size_t)64 * lda, Alds + slot * 4096 + 2048 + w * 512);
    };
    auto stageBh = [&](int slot, int t, int h) {   // [128][32] half, 2 GLL
        const ushort* g = pB + (size_t)t * 32 + (size_t)(h * 128) * K;
        ushort* l = Blds + slot * BSLOT + h * 4096 + w * 512;
        GLL16(g, l);
        GLL16(g + (size_t)64 * K, l + 2048);
    };

    // swizzled ds_read chunk offset (ushort units)
    int qsw = (quad ^ ((lm >> 1) & 3)) * 8;

    f32x4 zero = {0.f, 0.f, 0.f, 0.f};
    f32x4 acc[4][BNF];
#pragma unroll
    for (int i = 0; i < 4; i++)
#pragma unroll
        for (int jj = 0; jj < BNF; jj++) acc[i][jj] = zero;

    int nkt = K >> 5;                              // K-tiles of 32 (>= 32 here)

    // prologue: A(0)->s0, B(0)->s0, B(1)->s1; gate leaves B(1) in flight
    stageA(0, 0);
    stageBh(0, 0, 0);
    if constexpr (BNF == 8) stageBh(0, 0, 1);
    stageBh(1, 1, 0);
    if constexpr (BNF == 8) stageBh(1, 1, 1);
    __builtin_amdgcn_sched_barrier(0);
    if constexpr (BNF == 8) { asm volatile("s_waitcnt vmcnt(4)" ::: "memory"); }
    else                    { asm volatile("s_waitcnt vmcnt(2)" ::: "memory"); }
    __builtin_amdgcn_s_barrier();
    __builtin_amdgcn_sched_barrier(0);

    int sA = 0, sB = 0;
    for (int t = 0; t < nkt; ++t) {
        const bool stA = (t + 1 < nkt);
        const bool stB = (t + 2 < nkt);
        int sB2 = sB + 2; if (sB2 >= 3) sB2 -= 3;
        const ushort* Ab = Alds + sA * 4096  + (wm * 64 + lm) * 32;
        const ushort* Bb = Blds + sB * BSLOT + (wn * (BNF * 16) + lm) * 32;
        s16x8 a[4], b0[BNF / 2], b1[BNF / 2];

        // issue next-tile stages first: HBM latency spans the whole iter
        if (stA) stageA(sA ^ 1, t + 1);
        if (stB) {
            stageBh(sB2, t + 2, 0);
            if constexpr (BNF == 8) stageBh(sB2, t + 2, 1);
        }
        __builtin_amdgcn_sched_barrier(0);

        // read current tile frags; MFMA (compiler inserts lgkmcnt)
#pragma unroll
        for (int m = 0; m < 4; m++)
            a[m] = *(const s16x8*)(Ab + m * 512 + qsw);
#pragma unroll
        for (int nf = 0; nf < BNF / 2; nf++)
            b0[nf] = *(const s16x8*)(Bb + nf * 512 + qsw);
        __builtin_amdgcn_s_setprio(1);
#pragma unroll
        for (int m = 0; m < 4; m++)
#pragma unroll
            for (int nf = 0; nf < BNF / 2; nf++)
                acc[m][nf] = __builtin_amdgcn_mfma_f32_16x16x32_bf16(a[m], b0[nf], acc[m][nf], 0, 0, 0);
#pragma unroll
        for (int nf = 0; nf < BNF / 2; nf++)
            b1[nf] = *(const s16x8*)(Bb + (nf + BNF / 2) * 512 + qsw);
#pragma unroll
        for (int m = 0; m < 4; m++)
#pragma unroll
            for (int nf = 0; nf < BNF / 2; nf++)
                acc[m][nf + BNF / 2] = __builtin_amdgcn_mfma_f32_16x16x32_bf16(a[m], b1[nf], acc[m][nf + BNF / 2], 0, 0, 0);
        __builtin_amdgcn_s_setprio(0);

        // single gate + barrier per iteration
        __builtin_amdgcn_sched_barrier(0);
        if (stB) {
            if constexpr (BNF == 8) { asm volatile("s_waitcnt vmcnt(4)" ::: "memory"); }
            else                    { asm volatile("s_waitcnt vmcnt(2)" ::: "memory"); }
        } else if (stA) {
            asm volatile("s_waitcnt vmcnt(0)" ::: "memory");
        }
        if (stA) {
            __builtin_amdgcn_s_barrier();
            __builtin_amdgcn_sched_barrier(0);
        }

        sA ^= 1;
        sB += 1; if (sB >= 3) sB -= 3;
    }

    if (vtg && col0 >= 2048) {
        // V part: write transposed [B*H*HS][T], 4 consecutive t per ushort4
#pragma unroll
        for (int m = 0; m < 4; m++) {
            int r0 = row0 + wm * 64 + m * 16 + quad * 4;   // t base (mult of 4)
            int bb = r0 >> 11;
            int t  = r0 & (Tq - 1);
#pragma unroll
            for (int nf = 0; nf < BNF; nf++) {
                int hsg = col0 - 2048 + wn * (BNF * 16) + nf * 16 + lm;   // 0..1023
                ushort4 u;
                u.x = f2bf(acc[m][nf][0]);
                u.y = f2bf(acc[m][nf][1]);
                u.z = f2bf(acc[m][nf][2]);
                u.w = f2bf(acc[m][nf][3]);
                *(ushort4*)(vtg + ((size_t)(bb * Hq + (hsg >> 6)) * HSq + (hsg & 63)) * Tq + t) = u;
            }
        }
        return;
    }

    float bcol[BNF];
#pragma unroll
    for (int nf = 0; nf < BNF; nf++)
        bcol[nf] = bias ? bias[col0 + wn * (BNF * 16) + nf * 16 + lm] : 0.f;

#pragma unroll
    for (int m = 0; m < 4; m++) {
#pragma unroll
        for (int p = 0; p < 4; p++) {
            int r = row0 + wm * 64 + m * 16 + quad * 4 + p;
#pragma unroll
            for (int nf = 0; nf < BNF; nf++) {
                int cc = col0 + wn * (BNF * 16) + nf * 16 + lm;
                float v = acc[m][nf][p] + bcol[nf];
                if (relu) v = fmaxf(v, 0.f);
                if (resid) v += resid[(size_t)r * ldc + cc];
                if (out_bf16) ((ushort*)Cp)[(size_t)r * ldc + cc] = f2bf(v);
                else          ((float*)Cp)[(size_t)r * ldc + cc] = v;
            }
        }
    }
}

// ---------------- MFMA flash attention, complement-paired q-tiles ----------------
__global__ __launch_bounds__(256) void attn_mfma(const ushort* __restrict__ qkv,
                                                 const ushort* __restrict__ VtG,
                                                 ushort* __restrict__ o16) {
    __shared__ ushort Ks[64 * 72];
    __shared__ ushort Vt[64 * 64];
    __shared__ ushort Ps[4 * 16 * 72];

    int gid = blockIdx.x;
    int b  = gid >> 8;
    int hh = (gid >> 4) & 15;
    int pr = (gid + 7 * b) & 15;
    int qa = pr;
    int qb = 31 - pr;

    int tid = threadIdx.x;
    int w = tid >> 6, lane = tid & 63;
    int lm = lane & 15, quad = lane >> 4;

    const int rs3 = 3 * Dq;
    const ushort* qbase = qkv + (size_t)(b * Tq) * rs3 + hh * HSq;
    int qra = qa * 64 + w * 16 + lm;
    int qrb = qb * 64 + w * 16 + lm;
    s16x8 aqa0 = *(const s16x8*)(qbase + (size_t)qra * rs3 + quad * 8);
    s16x8 aqa1 = *(const s16x8*)(qbase + (size_t)qra * rs3 + 32 + quad * 8);
    s16x8 aqb0 = *(const s16x8*)(qbase + (size_t)qrb * rs3 + quad * 8);
    s16x8 aqb1 = *(const s16x8*)(qbase + (size_t)qrb * rs3 + 32 + quad * 8);

    s16x8 ones;
#pragma unroll
    for (int j = 0; j < 8; j++) ones[j] = (short)0x3F80;

    f32x4 zero = {0.f, 0.f, 0.f, 0.f};
    f32x4 oa[4], ob[4];
#pragma unroll
    for (int nt = 0; nt < 4; nt++) { oa[nt] = zero; ob[nt] = zero; }
    f32x4 la = zero, lb = zero;

    const ushort* kbase = qkv + (size_t)(b * Tq) * rs3 + Dq + hh * HSq;
    const ushort* vtb = VtG + (size_t)((b * Hq + hh) * HSq) * Tq;

    int kr = tid >> 3, kc = (tid & 7) * 8;
    int vh = tid >> 2, vc0 = (tid & 3) * 8;
    int vswz = (((vh >> 3) ^ vh) & 7) << 3;

    s16x8 kp0 = *(const s16x8*)(kbase + (size_t)kr * rs3 + kc);
    s16x8 kp1 = *(const s16x8*)(kbase + (size_t)(kr + 32) * rs3 + kc);
    s16x8 vp0 = *(const s16x8*)(vtb + (size_t)vh * Tq + vc0);
    s16x8 vp1 = *(const s16x8*)(vtb + (size_t)vh * Tq + vc0 + 32);

    auto do_tile = [&](const s16x8& aq0, const s16x8& aq1,
                       f32x4 (&o_acc)[4], f32x4& l_acc, int diag) {
        f32x4 sacc[4];
#pragma unroll
        for (int kt2 = 0; kt2 < 4; kt2++) {
            const ushort* krp = &Ks[(kt2 * 16 + lm) * 72 + quad * 8];
            s16x8 bk0 = *(const s16x8*)krp;
            s16x8 bk1 = *(const s16x8*)(krp + 32);
            f32x4 t = __builtin_amdgcn_mfma_f32_16x16x32_bf16(aq0, bk0, zero, 0, 0, 0);
            sacc[kt2] = __builtin_amdgcn_mfma_f32_16x16x32_bf16(aq1, bk1, t, 0, 0, 0);
        }
        if (diag) {
#pragma unroll
            for (int kt2 = 0; kt2 < 4; kt2++)
#pragma unroll
                for (int r = 0; r < 4; r++)
                    if (kt2 * 16 + lm > w * 16 + quad * 4 + r) sacc[kt2][r] = -1e30f;
        }
#pragma unroll
        for (int kt2 = 0; kt2 < 4; kt2++)
#pragma unroll
            for (int r = 0; r < 4; r++)
                Ps[(w * 16 + quad * 4 + r) * 72 + kt2 * 16 + lm] = f2bf(__expf(sacc[kt2][r]));

        s16x8 ap0 = *(const s16x8*)&Ps[(w * 16 + lm) * 72 + quad * 8];
        s16x8 ap1 = *(const s16x8*)&Ps[(w * 16 + lm) * 72 + 32 + quad * 8];

#pragma unroll
        for (int nt = 0; nt < 4; nt++) {
            int n = nt * 16 + lm;
            int swz = (((n >> 3) ^ n) & 7) << 3;
            s16x8 bv0 = *(const s16x8*)&Vt[n * 64 + ((quad * 8) ^ swz)];
            s16x8 bv1 = *(const s16x8*)&Vt[n * 64 + ((32 + quad * 8) ^ swz)];
            f32x4 t = __builtin_amdgcn_mfma_f32_16x16x32_bf16(ap0, bv0, o_acc[nt], 0, 0, 0);
            o_acc[nt] = __builtin_amdgcn_mfma_f32_16x16x32_bf16(ap1, bv1, t, 0, 0, 0);
        }
        f32x4 t2 = __builtin_amdgcn_mfma_f32_16x16x32_bf16(ap0, ones, l_acc, 0, 0, 0);
        l_acc = __builtin_amdgcn_mfma_f32_16x16x32_bf16(ap1, ones, t2, 0, 0, 0);
    };

    for (int kt = 0; kt <= qb; kt++) {
        __syncthreads();
        *(s16x8*)&Ks[kr * 72 + kc] = kp0;
        *(s16x8*)&Ks[(kr + 32) * 72 + kc] = kp1;
        *(s16x8*)&Vt[vh * 64 + (vc0 ^ vswz)] = vp0;
        *(s16x8*)&Vt[vh * 64 + ((vc0 + 32) ^ vswz)] = vp1;
        __syncthreads();

        if (kt < qb) {
            const ushort* kb = kbase + (size_t)((kt + 1) * 64) * rs3;
            kp0 = *(const s16x8*)(kb + (size_t)kr * rs3 + kc);
            kp1 = *(const s16x8*)(kb + (size_t)(kr + 32) * rs3 + kc);
            const ushort* vb = vtb + (size_t)vh * Tq + (kt + 1) * 64;
            vp0 = *(const s16x8*)(vb + vc0);
            vp1 = *(const s16x8*)(vb + vc0 + 32);
        }

        do_tile(aqb0, aqb1, ob, lb, kt == qb);
        if (kt <= qa)
            do_tile(aqa0, aqa1, oa, la, kt == qa);
    }

#pragma unroll
    for (int r = 0; r < 4; r++) {
        float inva = 1.f / la[r];
        float invb = 1.f / lb[r];
        size_t rowa = (size_t)(b * Tq + qa * 64 + w * 16 + quad * 4 + r);
        size_t rowb = (size_t)(b * Tq + qb * 64 + w * 16 + quad * 4 + r);
#pragma unroll
        for (int nt = 0; nt < 4; nt++) {
            o16[rowa * Dq + hh * HSq + nt * 16 + lm] = f2bf(oa[nt][r] * inva);
            o16[rowb * Dq + hh * HSq + nt * 16 + lm] = f2bf(ob[nt][r] * invb);
        }
    }
}

extern "C" void kernel_launch(void* const* d_in, const int* in_sizes, int n_in,
                              void* d_out, int out_size, void* d_ws, size_t ws_size,
                              hipStream_t stream) {
    const float* x   = (const float*)d_in[0];
    const float* Wq  = (const float*)d_in[1];
    const float* Wk  = (const float*)d_in[2];
    const float* Wv  = (const float*)d_in[3];
    const float* Wp  = (const float*)d_in[4];
    const float* bp  = (const float*)d_in[5];
    const float* W1  = (const float*)d_in[6];
    const float* b1  = (const float*)d_in[7];
    const float* W2  = (const float*)d_in[8];
    const float* b2  = (const float*)d_in[9];
    const float* g1  = (const float*)d_in[10];
    const float* be1 = (const float*)d_in[11];
    const float* g2  = (const float*)d_in[12];
    const float* be2 = (const float*)d_in[13];
    float* out = (float*)d_out;

    const size_t MB = 1u << 20;
    char* ws = (char*)d_ws;
    float*  slotA = (float*)(ws);              // [0,32)   LN1 out -> LN2 out, fp32
    ushort* qkv   = (ushort*)(ws + 32 * MB);   // [32,80)  qkv bf16 (V third unused)
    float*  pbuf  = (float*)(ws + 32 * MB);    // [32,64)  proj out fp32 (qkv dead after attn)
    ushort* u16   = (ushort*)(ws + 32 * MB);   // [32,96)  FF1 out bf16 (pbuf dead after LN2)
    ushort* slotC = (ushort*)(ws + 96 * MB);   // [96,112) h16 -> o16 -> h2_16, bf16
    ushort* WqkvT = (ushort*)(ws + 112 * MB);  // 6 MB
    ushort* WpT   = (ushort*)(ws + 118 * MB);  // 2 MB
    ushort* W1T   = (ushort*)(ws + 120 * MB);  // 8 MB
    ushort* W2T   = (ushort*)(ws + 128 * MB);  // 8 MB
    ushort* VtG   = (ushort*)(ws + 136 * MB);  // 16 MB V^T bf16 [B*H*HS][T]

    const int rows = Bq * Tq;                  // 8192

    hipLaunchKernelGGL(repack_qkvT, dim3(3 * 16 * 16), dim3(256), 0, stream, Wq, Wk, Wv, WqkvT);
    hipLaunchKernelGGL(transpose_cvt, dim3(Dq / 64, Dq / 64), dim3(256), 0, stream, Wp, WpT, Dq, Dq);
    hipLaunchKernelGGL(transpose_cvt, dim3(4 * Dq / 64, Dq / 64), dim3(256), 0, stream, W1, W1T, Dq, 4 * Dq);
    hipLaunchKernelGGL(transpose_cvt, dim3(Dq / 64, 4 * Dq / 64), dim3(256), 0, stream, W2, W2T, 4 * Dq, Dq);

    // 1. LN1
    hipLaunchKernelGGL(ln_bf16, dim3(rows), dim3(256), 0, stream, x, g1, be1, slotA, slotC);
    // 2. QKV GEMM (BN=256) -> Q,K into qkv bf16; V transposed into VtG  (64 x 12 = 768 blocks)
    hipLaunchKernelGGL(gemm_bf16<8>, dim3((rows / 128) * (3 * Dq / 256)), dim3(256), 0, stream,
                       slotC, WqkvT, (const float*)nullptr, (const float*)nullptr, (void*)qkv, VtG,
                       rows, 3 * Dq, Dq, Dq, 3 * Dq, 0, 1, 8);
    // 3. attention (complement-paired q-tiles) -> slotC bf16
    hipLaunchKernelGGL(attn_mfma, dim3(Bq * Hq * 16), dim3(256), 0, stream, qkv, VtG, slotC);
    // 4. proj + bias + residual(slotA) -> pbuf fp32  (BN=128, 64 x 8 = 512 blocks)
    hipLaunchKernelGGL(gemm_bf16<4>, dim3((rows / 128) * (Dq / 128)), dim3(256), 0, stream,
                       slotC, WpT, bp, slotA, (void*)pbuf, (ushort*)nullptr,
                       rows, Dq, Dq, Dq, Dq, 0, 0, 8);
    // 5. LN2
    hipLaunchKernelGGL(ln_bf16, dim3(rows), dim3(256), 0, stream, pbuf, g2, be2, slotA, slotC);
    // 6. FF1 + bias + relu (BN=256) -> u16 bf16  (64 x 16 = 1024 blocks)
    hipLaunchKernelGGL(gemm_bf16<8>, dim3((rows / 128) * (4 * Dq / 256)), dim3(256), 0, stream,
                       slotC, W1T, b1, (const float*)nullptr, (void*)u16, (ushort*)nullptr,
                       rows, 4 * Dq, Dq, Dq, 4 * Dq, 1, 1, 8);
    // 7. FF2 + bias + residual(slotA) (BN=128) -> out fp32  (64 x 8 = 512 blocks; sr=4 for K=4096)
    hipLaunchKernelGGL(gemm_bf16<4>, dim3((rows / 128) * (Dq / 128)), dim3(256), 0, stream,
                       u16, W2T, b2, slotA, (void*)out, (ushort*)nullptr,
                       rows, Dq, 4 * Dq, 4 * Dq, Dq, 0, 0, 4);
}